// Round 3
// baseline (536.232 us; speedup 1.0000x reference)
//
#include <hip/hip_runtime.h>

typedef __attribute__((ext_vector_type(8))) short short8;
typedef __attribute__((ext_vector_type(4))) float floatx4;

#define T_SIZE 32768
#define OBS    256
#define H      512
#define NBLK   8       // N-tiles (256 cols each over N=2048)
#define MBLK   128     // M-tiles (256 rows each)

__device__ __forceinline__ unsigned short f2bf(float f){
    union { float f; unsigned u; } v; v.f = f;
    unsigned u = v.u;
    u += 0x7FFFu + ((u >> 16) & 1u);   // round-to-nearest-even
    return (unsigned short)(u >> 16);
}
__device__ __forceinline__ float bf2f(unsigned short u){
    union { unsigned u; float f; } v; v.u = ((unsigned)u) << 16; return v.f;
}

// async global->LDS, 16B per lane; lds base must be wave-uniform (HW adds lane*16)
#define GLOAD_LDS16(g, l) \
    __builtin_amdgcn_global_load_lds((const __attribute__((address_space(1))) unsigned*)(g), \
                                     (__attribute__((address_space(3))) unsigned*)(l), 16, 0, 0)

// ---- cast x [T,OBS] fp32 -> bf16, vectorized ----
__global__ void cast_x_kernel(const float* __restrict__ x, unsigned short* __restrict__ xb, int n4){
    int i = blockIdx.x * 256 + threadIdx.x;
    if (i < n4){
        float4 v = ((const float4*)x)[i];
        ushort4 o;
        o.x = f2bf(v.x); o.y = f2bf(v.y); o.z = f2bf(v.z); o.w = f2bf(v.w);
        ((ushort4*)xb)[i] = o;
    }
}

// ---- transpose+cast 4 weights W[K][512] fp32 -> interleaved [h/16][slot][16h][K] bf16 ----
__global__ void tcast4_kernel(const float* __restrict__ W0, const float* __restrict__ W1,
                              const float* __restrict__ W2, const float* __restrict__ W3,
                              unsigned short* __restrict__ dst, int K, int KH){
    int idx = blockIdx.x * 256 + threadIdx.x;
    if (idx >= 4 * KH) return;
    int s   = idx / KH;
    int rem = idx - s * KH;
    int k = rem >> 9;            // H == 512
    int h = rem & 511;
    const float* W = (s == 0) ? W0 : (s == 1) ? W1 : (s == 2) ? W2 : W3;
    int b = h >> 4, hh = h & 15;
    dst[(size_t)((b * 4 + s) * 16 + hh) * K + k] = f2bf(W[(size_t)k * H + h]);
}

// ---- fused 4-matrix GEMM, 256x256 tile, 8 waves, phase-split K-loop ----
// ---- + FULLY FUSED SSM SCAN via decoupled lookback; writes y=C*h bf16 [T][512] ----
// xb: [T][K] bf16.  wt: [2048 rows][K] bf16, row r=(b*4+s)*16+hh (slot s: 0=in,1=B,2=C,3=d).
// Lookback state per (nb,mb): AggP/AggH/Pref [NBLK][MBLK][64] fp32, status [NBLK][MBLK]
// (0=none, 1=AGG published, 2=PREFIX published). Chain runs over mb for fixed nb;
// flat dispatch id is strictly increasing in mb for fixed nb -> lookback is deadlock-free.
template<int K>
__global__ __launch_bounds__(512, 1) void gemm_layer_kernel(
    const unsigned short* __restrict__ xb,
    const unsigned short* __restrict__ wt,
    const float* __restrict__ A_log,
    unsigned short* __restrict__ y,
    float* __restrict__ AggP, float* __restrict__ AggH, float* __restrict__ Pref,
    unsigned int* status)
{
    // 4 K-tile buffers x (A 8192 shorts | B 8192 shorts) = 128 KB; epilogue reuses it
    __shared__ unsigned short SM[4][16384];
    __shared__ float hp[64];

    const int tid  = threadIdx.x;
    const int wave = tid >> 6;           // 0..7
    const int lane = tid & 63;
    const int ml   = lane & 15;
    const int quad = lane >> 4;
    const int wm   = wave >> 2;          // 0..1 : M half (128 rows)
    const int wn   = wave & 3;           // 0..3 : N quarter (64 B-rows = 16 h x 4 slots)

    // XCD-aware swizzle; for fixed nb, flat is strictly increasing in mb (lookback-safe)
    const int flat = blockIdx.y * 8 + blockIdx.x;
    const int xcd  = flat & 7;
    const int j    = flat >> 3;
    const int nb   = j & 7;                  // 0..7  : 256-wide N tile (64 h x 4 slots)
    const int mb   = (j >> 3) * 8 + xcd;     // 0..127: 256-tall M tile
    const int m0   = mb * 256;

    const int srow = tid >> 2;                                 // 0..127
    const int sel  = ((tid & 3) ^ ((tid >> 3) & 3)) * 8;       // staging XOR swizzle
    const int swz  = (ml >> 1) & 3;                            // read-side XOR swizzle

    const unsigned short* pa0 = xb + (size_t)(m0 + srow) * K + sel;
    const unsigned short* pa1 = pa0 + (size_t)128 * K;
    const unsigned short* pb0 = wt + (size_t)(nb * 256 + srow) * K + sel;
    const unsigned short* pb1 = pb0 + (size_t)128 * K;

    // wave-uniform LDS staging bases (shorts)
    const int ldsA0 = wave * 512;
    const int ldsA1 = 4096  + wave * 512;
    const int ldsB0 = 8192  + wave * 512;
    const int ldsB1 = 12288 + wave * 512;

    // lane-dependent LDS read bases (elements)
    const int rbaseA = (wm * 128 + ml) * 32 + (quad ^ swz) * 8;
    const int rbaseB = (wn * 64  + ml) * 32 + (quad ^ swz) * 8;

    floatx4 acc[8][4];
    #pragma unroll
    for (int m = 0; m < 8; m++)
        #pragma unroll
        for (int n = 0; n < 4; n++)
            acc[m][n] = (floatx4)(0.0f);

    constexpr int NK = K >> 5;   // 8 (layer0) or 16 (layer1)

#define STAGE_A(kt_) { const int b_ = (kt_) & 3; const int ko_ = (kt_) * 32; \
        GLOAD_LDS16(pa0 + ko_, &SM[b_][ldsA0]); \
        GLOAD_LDS16(pa1 + ko_, &SM[b_][ldsA1]); }
#define STAGE_B(kt_) { const int b_ = (kt_) & 3; const int ko_ = (kt_) * 32; \
        GLOAD_LDS16(pb0 + ko_, &SM[b_][ldsB0]); \
        GLOAD_LDS16(pb1 + ko_, &SM[b_][ldsB1]); }

    // prologue: stage K-tiles 0,1,2 (prefetch-3); wait tile 0 only
    STAGE_A(0); STAGE_B(0);
    STAGE_A(1); STAGE_B(1);
    STAGE_A(2); STAGE_B(2);
    asm volatile("s_waitcnt vmcnt(8)" ::: "memory");
    __builtin_amdgcn_s_barrier();
    __builtin_amdgcn_sched_barrier(0);

    #pragma unroll
    for (int kt = 0; kt < NK; ++kt){
        const unsigned short* SA = &SM[kt & 3][0];
        const unsigned short* SB = SA + 8192;

        // ---- phase 0: m 0..3 quadrant ----
        short8 av[4], bv[4];
        #pragma unroll
        for (int m = 0; m < 4; m++) av[m] = *(const short8*)(SA + rbaseA + m * 512);
        #pragma unroll
        for (int n = 0; n < 4; n++) bv[n] = *(const short8*)(SB + rbaseB + n * 512);
        if (kt + 3 < NK) STAGE_A(kt + 3);
        __builtin_amdgcn_s_barrier();
        asm volatile("s_waitcnt lgkmcnt(0)" ::: "memory");
        __builtin_amdgcn_sched_barrier(0);
        __builtin_amdgcn_s_setprio(1);
        #pragma unroll
        for (int m = 0; m < 4; m++)
            #pragma unroll
            for (int n = 0; n < 4; n++)
                acc[m][n] = __builtin_amdgcn_mfma_f32_16x16x32_bf16(av[m], bv[n], acc[m][n], 0, 0, 0);
        __builtin_amdgcn_s_setprio(0);
        __builtin_amdgcn_s_barrier();
        __builtin_amdgcn_sched_barrier(0);

        // ---- phase 1: m 4..7 quadrant (reuse bv) ----
        short8 aw[4];
        #pragma unroll
        for (int m = 0; m < 4; m++) aw[m] = *(const short8*)(SA + rbaseA + (m + 4) * 512);
        if (kt + 3 < NK) STAGE_B(kt + 3);
        __builtin_amdgcn_s_barrier();
        asm volatile("s_waitcnt lgkmcnt(0)" ::: "memory");
        __builtin_amdgcn_sched_barrier(0);
        __builtin_amdgcn_s_setprio(1);
        #pragma unroll
        for (int m = 0; m < 4; m++)
            #pragma unroll
            for (int n = 0; n < 4; n++)
                acc[m + 4][n] = __builtin_amdgcn_mfma_f32_16x16x32_bf16(aw[m], bv[n], acc[m + 4][n], 0, 0, 0);
        __builtin_amdgcn_s_setprio(0);
        if (kt + 1 < NK){
            if (kt + 3 < NK)       { asm volatile("s_waitcnt vmcnt(8)" ::: "memory"); }
            else if (kt + 3 == NK) { asm volatile("s_waitcnt vmcnt(4)" ::: "memory"); }
            else                   { asm volatile("s_waitcnt vmcnt(0)" ::: "memory"); }
        }
        __builtin_amdgcn_s_barrier();
        __builtin_amdgcn_sched_barrier(0);
    }
    __syncthreads();   // full drain before epilogue reuses SM

#undef STAGE_A
#undef STAGE_B

    // ==== fused scan epilogue ====
    // LDS map (bytes): segbuf [64 segs][64 cols] float2 @0 (32KB); ystage shorts @65536 (32KB)
    unsigned short* SMe = &SM[0][0];
    float2* segbuf = (float2*)SMe;
    unsigned short* ystage = SMe + 32768;

    const int hcol = wn * 16 + ml;             // 0..63 h within this nb block
    const float Aneg = -expf(A_log[(nb * 4 + wn) * 16 + ml]);

    // E1: per-element g/bx/C (bf16-quantized, identical to previous verified math),
    //     per-4-row segment (p,hh) aggregates -> segbuf
    unsigned gpk[16], bpk[16], cpk[16];
    #pragma unroll
    for (int m = 0; m < 8; m++){
        float p = 1.0f, hh = 0.0f;
        #pragma unroll
        for (int r = 0; r < 4; r++){
            float dv = acc[m][3][r];
            float delta = 1.0f / (1.0f + expf(-dv));
            unsigned short gb = f2bf(delta * Aneg);
            float a = expf(bf2f(gb));
            unsigned short bb = f2bf(acc[m][1][r] * acc[m][0][r]);
            unsigned short cb = f2bf(acc[m][2][r]);
            if ((r & 1) == 0){
                gpk[m*2 + (r>>1)] = (unsigned)gb;
                bpk[m*2 + (r>>1)] = (unsigned)bb;
                cpk[m*2 + (r>>1)] = (unsigned)cb;
            } else {
                gpk[m*2 + (r>>1)] |= ((unsigned)gb) << 16;
                bpk[m*2 + (r>>1)] |= ((unsigned)bb) << 16;
                cpk[m*2 + (r>>1)] |= ((unsigned)cb) << 16;
            }
            hh = fmaf(a, hh, bf2f(bb));
            p *= a;
        }
        const int sidx = wm * 32 + m * 4 + quad;     // seg index in t-order (trow/4)
        segbuf[sidx * 64 + hcol] = make_float2(p, hh);
    }
    __syncthreads();

    // E3-E5: wave 0 (one lane per column): block scan, publish AGG, lookback, publish PREFIX
    if (tid < 64){
        float P = 1.0f, Hh = 0.0f;
        for (int s = 0; s < 64; s++){
            float2 ph = segbuf[s * 64 + tid];
            segbuf[s * 64 + tid] = make_float2(P, Hh);   // exclusive prefix as affine pair
            Hh = fmaf(ph.x, Hh, ph.y);
            P *= ph.x;
        }
        const size_t base = ((size_t)nb * MBLK + mb) * 64;
        AggP[base + tid] = P;
        AggH[base + tid] = Hh;
        __threadfence();
        if (tid == 0)
            __hip_atomic_store(&status[nb * MBLK + mb], 1u, __ATOMIC_RELEASE, __HIP_MEMORY_SCOPE_AGENT);

        float hin = 0.0f;
        if (mb > 0){
            float Pc = 1.0f, Hc = 0.0f;
            int jj = mb - 1;
            for (;;){
                unsigned st;
                do {
                    st = __hip_atomic_load(&status[nb * MBLK + jj], __ATOMIC_ACQUIRE, __HIP_MEMORY_SCOPE_AGENT);
                    st = __builtin_amdgcn_readfirstlane(st);
                    if (st == 0u) __builtin_amdgcn_s_sleep(1);
                } while (st == 0u);
                const size_t bj = ((size_t)nb * MBLK + jj) * 64;
                if (st == 2u){
                    float pf = Pref[bj + tid];
                    hin = fmaf(Pc, pf, Hc);
                    break;
                } else {
                    float pj = AggP[bj + tid];
                    float hj = AggH[bj + tid];
                    Hc = fmaf(Pc, hj, Hc);
                    Pc *= pj;
                    if (--jj < 0){ hin = Hc; break; }
                }
            }
        }
        float hout = fmaf(P, hin, Hh);
        Pref[base + tid] = hout;
        __threadfence();
        if (tid == 0)
            __hip_atomic_store(&status[nb * MBLK + mb], 2u, __ATOMIC_RELEASE, __HIP_MEMORY_SCOPE_AGENT);
        hp[tid] = hin;
    }
    __syncthreads();

    // E7: apply recurrence in-register, y = C*h -> ystage (row-major [256][64] bf16)
    {
        const float hin_b = hp[hcol];
        #pragma unroll
        for (int m = 0; m < 8; m++){
            const int sidx = wm * 32 + m * 4 + quad;
            float2 pp = segbuf[sidx * 64 + hcol];
            float h = fmaf(pp.x, hin_b, pp.y);
            #pragma unroll
            for (int r = 0; r < 4; r++){
                unsigned short gb = (unsigned short)((gpk[m*2 + (r>>1)] >> ((r & 1) * 16)) & 0xFFFFu);
                unsigned short bb = (unsigned short)((bpk[m*2 + (r>>1)] >> ((r & 1) * 16)) & 0xFFFFu);
                unsigned short cb = (unsigned short)((cpk[m*2 + (r>>1)] >> ((r & 1) * 16)) & 0xFFFFu);
                float a = expf(bf2f(gb));
                h = fmaf(a, h, bf2f(bb));
                const int trow = wm * 128 + m * 16 + quad * 4 + r;
                ystage[trow * 64 + hcol] = f2bf(bf2f(cb) * h);
            }
        }
    }
    __syncthreads();

    // E8: coalesced store of y tile: rows m0..m0+255, cols nb*64..+63 of [T][512]
    {
        const short8* ys8 = (const short8*)ystage;
        #pragma unroll
        for (int k = 0; k < 4; k++){
            int idx = k * 512 + tid;          // 0..2047
            int row = idx >> 3, c8 = idx & 7;
            *(short8*)(y + (size_t)(m0 + row) * H + nb * 64 + c8 * 8) = ys8[idx];
        }
    }
}

// ---- final: out[t][0:4] = y[t]@W_out + b_out + xb[t]@W_skip  (y,xb bf16; wave per row) ----
__global__ __launch_bounds__(256) void final_kernel(const unsigned short* __restrict__ y2,
                                                    const unsigned short* __restrict__ xb,
                                                    const float* __restrict__ Wout,
                                                    const float* __restrict__ bout,
                                                    const float* __restrict__ Wskip,
                                                    float* __restrict__ out){
    int wave = threadIdx.x >> 6;
    int lane = threadIdx.x & 63;
    int t = blockIdx.x * 4 + wave;
    float s0 = 0.f, s1 = 0.f, s2 = 0.f, s3 = 0.f;
    const float4* W4 = (const float4*)Wout;
    #pragma unroll
    for (int k = lane; k < H; k += 64){
        float yv = bf2f(y2[(size_t)t * H + k]);
        float4 w = W4[k];
        s0 = fmaf(yv, w.x, s0); s1 = fmaf(yv, w.y, s1);
        s2 = fmaf(yv, w.z, s2); s3 = fmaf(yv, w.w, s3);
    }
    const float4* S4 = (const float4*)Wskip;
    #pragma unroll
    for (int k = lane; k < OBS; k += 64){
        float xv = bf2f(xb[(size_t)t * OBS + k]);
        float4 w = S4[k];
        s0 = fmaf(xv, w.x, s0); s1 = fmaf(xv, w.y, s1);
        s2 = fmaf(xv, w.z, s2); s3 = fmaf(xv, w.w, s3);
    }
    #pragma unroll
    for (int off = 32; off > 0; off >>= 1){
        s0 += __shfl_down(s0, off);
        s1 += __shfl_down(s1, off);
        s2 += __shfl_down(s2, off);
        s3 += __shfl_down(s3, off);
    }
    if (lane == 0){
        out[(size_t)t * 4 + 0] = s0 + bout[0];
        out[(size_t)t * 4 + 1] = s1 + bout[1];
        out[(size_t)t * 4 + 2] = s2 + bout[2];
        out[(size_t)t * 4 + 3] = s3 + bout[3];
    }
}

extern "C" void kernel_launch(void* const* d_in, const int* in_sizes, int n_in,
                              void* d_out, int out_size, void* d_ws, size_t ws_size,
                              hipStream_t stream)
{
    const float* x     = (const float*)d_in[0];
    const float* W_in0 = (const float*)d_in[1];
    const float* W_B0  = (const float*)d_in[2];
    const float* W_C0  = (const float*)d_in[3];
    const float* W_d0  = (const float*)d_in[4];
    const float* A0    = (const float*)d_in[5];
    const float* W_in1 = (const float*)d_in[6];
    const float* W_B1  = (const float*)d_in[7];
    const float* W_C1  = (const float*)d_in[8];
    const float* W_d1  = (const float*)d_in[9];
    const float* A1    = (const float*)d_in[10];
    const float* Wout  = (const float*)d_in[11];
    const float* bout  = (const float*)d_in[12];
    const float* Wskip = (const float*)d_in[13];
    float* out = (float*)d_out;

    char* ws = (char*)d_ws;
    size_t off = 0;
    auto alloc = [&](size_t bytes) -> void* {
        void* p = ws + off;
        off += (bytes + 255) & ~(size_t)255;
        return p;
    };
    unsigned short* xb  = (unsigned short*)alloc((size_t)T_SIZE * OBS * 2);
    unsigned short* y0  = (unsigned short*)alloc((size_t)T_SIZE * H * 2);
    unsigned short* y1  = (unsigned short*)alloc((size_t)T_SIZE * H * 2);
    unsigned short* Wt0 = (unsigned short*)alloc((size_t)4 * H * OBS * 2);
    unsigned short* Wt1 = (unsigned short*)alloc((size_t)4 * H * H * 2);
    float* AggP = (float*)alloc((size_t)NBLK * MBLK * 64 * 4);
    float* AggH = (float*)alloc((size_t)NBLK * MBLK * 64 * 4);
    float* Pref = (float*)alloc((size_t)NBLK * MBLK * 64 * 4);
    unsigned int* st0 = (unsigned int*)alloc((size_t)NBLK * MBLK * 4);
    unsigned int* st1 = (unsigned int*)alloc((size_t)NBLK * MBLK * 4);
    (void)ws_size; (void)in_sizes; (void)n_in; (void)out_size;

    // zero lookback statuses for both layers (must be fresh every launch)
    hipMemsetAsync(st0, 0, (size_t)NBLK * MBLK * 4 * 2, stream);   // st0 and st1 contiguous

    // ---- precision casts / weight transposes (interleaved layout) ----
    cast_x_kernel<<<(T_SIZE * OBS / 4 + 255) / 256, 256, 0, stream>>>(x, xb, T_SIZE * OBS / 4);
    tcast4_kernel<<<(4 * OBS * H + 255) / 256, 256, 0, stream>>>(W_in0, W_B0, W_C0, W_d0, Wt0, OBS, OBS * H);
    tcast4_kernel<<<(4 * H   * H + 255) / 256, 256, 0, stream>>>(W_in1, W_B1, W_C1, W_d1, Wt1, H,   H * H);

    dim3 ggrid(8, 128);                  // flat-swizzled inside the kernel (1024 blocks)

    // ---- layer 0: GEMM + fused scan -> y0 ----
    gemm_layer_kernel<OBS><<<ggrid, 512, 0, stream>>>(xb, Wt0, A0, y0, AggP, AggH, Pref, st0);

    // ---- layer 1: GEMM + fused scan -> y1 ----
    gemm_layer_kernel<H><<<ggrid, 512, 0, stream>>>(y0, Wt1, A1, y1, AggP, AggH, Pref, st1);

    // ---- output head ----
    final_kernel<<<T_SIZE / 4, 256, 0, stream>>>(y1, xb, Wout, bout, Wskip, out);
}

// Round 4
// 328.320 us; speedup vs baseline: 1.6333x; 1.6333x over previous
//
#include <hip/hip_runtime.h>

typedef __attribute__((ext_vector_type(8))) short short8;
typedef __attribute__((ext_vector_type(4))) float floatx4;

#define T_SIZE 32768
#define OBS    256
#define H      512
#define NC     1024    // scan chunks
#define CHUNK  32      // T_SIZE / NC
#define NGRP   64      // scan2 groups
#define GCH    16      // chunks per group
#define SLAB   ((size_t)T_SIZE * 32)   // one h-block slab in tiled layout

__device__ __forceinline__ unsigned short f2bf(float f){
    union { float f; unsigned u; } v; v.f = f;
    unsigned u = v.u;
    u += 0x7FFFu + ((u >> 16) & 1u);   // round-to-nearest-even
    return (unsigned short)(u >> 16);
}
__device__ __forceinline__ float bf2f(unsigned short u){
    union { unsigned u; float f; } v; v.u = ((unsigned)u) << 16; return v.f;
}

// async global->LDS, 16B per lane; lds base must be wave-uniform (HW adds lane*16)
#define GLOAD_LDS16(g, l) \
    __builtin_amdgcn_global_load_lds((const __attribute__((address_space(1))) unsigned*)(g), \
                                     (__attribute__((address_space(3))) unsigned*)(l), 16, 0, 0)

// ---- merged prep: cast x -> bf16 (blocks 0..8191), tcast W0 set (8192..10239, K=256),
// ----              tcast W1 set (10240..14335, K=512). All ranges exact multiples.
__global__ void prep_kernel(const float* __restrict__ x, unsigned short* __restrict__ xb,
                            const float* __restrict__ A0W0, const float* __restrict__ A0W1,
                            const float* __restrict__ A0W2, const float* __restrict__ A0W3,
                            unsigned short* __restrict__ Wt0,
                            const float* __restrict__ A1W0, const float* __restrict__ A1W1,
                            const float* __restrict__ A1W2, const float* __restrict__ A1W3,
                            unsigned short* __restrict__ Wt1){
    const int b = blockIdx.x;
    const int tid = threadIdx.x;
    if (b < 8192){
        int i = b * 256 + tid;                       // n4 = 2097152 = 8192*256 exactly
        float4 v = ((const float4*)x)[i];
        ushort4 o;
        o.x = f2bf(v.x); o.y = f2bf(v.y); o.z = f2bf(v.z); o.w = f2bf(v.w);
        ((ushort4*)xb)[i] = o;
    } else if (b < 10240){
        const int K = OBS, KH = OBS * H;
        int idx = (b - 8192) * 256 + tid;            // 4*KH = 524288 = 2048*256 exactly
        int s   = idx / KH;
        int rem = idx - s * KH;
        int k = rem >> 9;
        int h = rem & 511;
        const float* W = (s == 0) ? A0W0 : (s == 1) ? A0W1 : (s == 2) ? A0W2 : A0W3;
        int bb = h >> 4, hh = h & 15;
        Wt0[(size_t)((bb * 4 + s) * 16 + hh) * K + k] = f2bf(W[(size_t)k * H + h]);
    } else {
        const int K = H, KH = H * H;
        int idx = (b - 10240) * 256 + tid;           // 4*KH = 1048576 = 4096*256 exactly
        int s   = idx / KH;
        int rem = idx - s * KH;
        int k = rem >> 9;
        int h = rem & 511;
        const float* W = (s == 0) ? A1W0 : (s == 1) ? A1W1 : (s == 2) ? A1W2 : A1W3;
        int bb = h >> 4, hh = h & 15;
        Wt1[(size_t)((bb * 4 + s) * 16 + hh) * K + k] = f2bf(W[(size_t)k * H + h]);
    }
}

// ---- fused 4-matrix GEMM (4-deep LDS pipeline, counted vmcnt, K templated) + epilogue + scan1 ----
// (verbatim round-1 verified kernel: 128x128 tile, 4 waves, 4x16KB ring, prefetch-3)
template<int K>
__global__ __launch_bounds__(256) void gemm_layer_kernel(
    const unsigned short* __restrict__ xb,
    const unsigned short* __restrict__ wt,
    const float* __restrict__ A_log,
    unsigned short* __restrict__ gT, unsigned short* __restrict__ bxT, unsigned short* __restrict__ CT,
    float* __restrict__ Pbuf, float* __restrict__ Hbuf)
{
    __shared__ unsigned short SM[4][8192];

    const int tid  = threadIdx.x;
    const int wave = tid >> 6;
    const int lane = tid & 63;
    const int ml   = lane & 15;
    const int quad = lane >> 4;
    const int wm   = wave & 1;
    const int wn   = wave >> 1;

    const int flat = blockIdx.y * 16 + blockIdx.x;
    const int xcd  = flat & 7;
    const int j    = flat >> 3;
    const int nb   = j & 15;                 // 0..15 : h block of 32
    const int mb   = (j >> 4) * 8 + xcd;     // 0..255 : t tile of 128
    const int m0   = mb * 128;

    const int srow = tid >> 2;
    const int sel  = (((tid & 3) ^ ((tid >> 3) & 3))) * 8;   // staging XOR swizzle
    const int swz  = (ml >> 1) & 3;                          // read-side XOR swizzle

    const unsigned short* pa0 = xb + (size_t)(m0 + srow) * K + sel;
    const unsigned short* pa1 = pa0 + (size_t)64 * K;
    const unsigned short* pb0 = wt + (size_t)(nb * 128 + srow) * K + sel;
    const unsigned short* pb1 = pb0 + (size_t)64 * K;

    const int ldsA0 = (wave * 64 + 0  ) * 8;
    const int ldsA1 = (wave * 64 + 256) * 8;

    const int rbaseA = (wm * 64 + ml) * 32 + (quad ^ swz) * 8;
    const int rbaseB = (wn * 64 + ml) * 32 + (quad ^ swz) * 8;

    floatx4 acc[4][4];
    #pragma unroll
    for (int i = 0; i < 4; i++)
        #pragma unroll
        for (int jj = 0; jj < 4; jj++)
            acc[i][jj] = (floatx4)(0.0f);

    constexpr int NK = K >> 5;   // 8 or 16

    // prologue: stage K-tiles 0,1,2 into bufs 0,1,2 (depth-3 prefetch)
    #pragma unroll
    for (int p = 0; p < 3; ++p){
        const int ko = p * 32;
        GLOAD_LDS16(pa0 + ko, &SM[p][ldsA0]);
        GLOAD_LDS16(pa1 + ko, &SM[p][ldsA1]);
        GLOAD_LDS16(pb0 + ko, &SM[p][4096 + ldsA0]);
        GLOAD_LDS16(pb1 + ko, &SM[p][4096 + ldsA1]);
    }
    asm volatile("s_waitcnt vmcnt(8)" ::: "memory");
    __builtin_amdgcn_s_barrier();
    __builtin_amdgcn_sched_barrier(0);

    #pragma unroll
    for (int kk = 0; kk < NK; ++kk){
        const int cur = kk & 3;

        if (kk + 3 < NK){
            const int ko  = (kk + 3) * 32;
            const int nb4 = (kk + 3) & 3;
            GLOAD_LDS16(pa0 + ko, &SM[nb4][ldsA0]);
            GLOAD_LDS16(pa1 + ko, &SM[nb4][ldsA1]);
            GLOAD_LDS16(pb0 + ko, &SM[nb4][4096 + ldsA0]);
            GLOAD_LDS16(pb1 + ko, &SM[nb4][4096 + ldsA1]);
        }

        short8 av[4], bv[4];
        #pragma unroll
        for (int i = 0; i < 4; i++)
            av[i] = *(const short8*)(&SM[cur][0] + rbaseA + i * 16 * 32);
        #pragma unroll
        for (int jj = 0; jj < 4; jj++)
            bv[jj] = *(const short8*)(&SM[cur][4096] + rbaseB + jj * 16 * 32);

        __builtin_amdgcn_s_setprio(1);
        #pragma unroll
        for (int i = 0; i < 4; i++)
            #pragma unroll
            for (int jj = 0; jj < 4; jj++)
                acc[i][jj] = __builtin_amdgcn_mfma_f32_16x16x32_bf16(av[i], bv[jj], acc[i][jj], 0, 0, 0);
        __builtin_amdgcn_s_setprio(0);

        if (kk + 1 < NK){
            const int hi = (kk + 3 < NK) ? (kk + 3) : (NK - 1);
            const int vm = 4 * (hi - (kk + 1));
            if (vm >= 8)      asm volatile("s_waitcnt vmcnt(8)" ::: "memory");
            else if (vm == 4) asm volatile("s_waitcnt vmcnt(4)" ::: "memory");
            else              asm volatile("s_waitcnt vmcnt(0)" ::: "memory");
            __builtin_amdgcn_s_barrier();
            __builtin_amdgcn_sched_barrier(0);
        }
    }
    __syncthreads();   // full drain before epilogue reuses SM

    // ---- epilogue (one LDS phase): g@0, bx@4096, C@8192 shorts; segbuf @24576 bytes ----
    unsigned short* SMe = &SM[0][0];
    float2* segbuf = (float2*)(SMe + 12288);  // [ch 4][seg 8][col 32] float2 = 8 KB
    const int col = wn * 16 + ml;             // 0..31 h within block
    const int h   = nb * 32 + col;
    const float Aneg = -expf(A_log[h]);

    #pragma unroll
    for (int i = 0; i < 4; i++){
        float p = 1.0f, hh = 0.0f;
        #pragma unroll
        for (int r = 0; r < 4; r++){
            int trow = wm * 64 + i * 16 + quad * 4 + r;   // C/D: row = quad*4 + reg
            float dv = acc[i][3][r];
            float delta = 1.0f / (1.0f + expf(-dv));
            unsigned short gb = f2bf(delta * Aneg);
            float a = expf(bf2f(gb));                     // rounded -> consistent with scan3
            unsigned short bb = f2bf(acc[i][1][r] * acc[i][0][r]);
            SMe[        trow * 32 + col] = gb;
            SMe[4096 +  trow * 32 + col] = bb;
            SMe[8192 +  trow * 32 + col] = f2bf(acc[i][2][r]);
            hh = fmaf(a, hh, bf2f(bb));
            p *= a;
        }
        const int ch = wm * 2 + (i >> 1);
        const int s  = (i & 1) * 4 + quad;
        segbuf[(ch * 8 + s) * 32 + col] = make_float2(p, hh);
    }
    __syncthreads();
    {
        const short8* s8 = (const short8*)SMe;
        short8* dg = (short8*)(gT  + (size_t)nb * SLAB + (size_t)m0 * 32);
        short8* db = (short8*)(bxT + (size_t)nb * SLAB + (size_t)m0 * 32);
        short8* dc = (short8*)(CT  + (size_t)nb * SLAB + (size_t)m0 * 32);
        dg[tid] = s8[tid];        dg[tid + 256] = s8[tid + 256];
        db[tid] = s8[512 + tid];  db[tid + 256] = s8[768 + tid];
        dc[tid] = s8[1024 + tid]; dc[tid + 256] = s8[1280 + tid];
    }
    if (tid < 128){
        const int ccol = tid & 31, ch = tid >> 5;
        float P = 1.0f, Hc = 0.0f;
        #pragma unroll
        for (int s = 0; s < 8; s++){
            float2 ph = segbuf[(ch * 8 + s) * 32 + ccol];
            Hc = fmaf(ph.x, Hc, ph.y);
            P *= ph.x;
        }
        const int c = mb * 4 + ch;
        Pbuf[(size_t)c * H + nb * 32 + ccol] = P;
        Hbuf[(size_t)c * H + nb * 32 + ccol] = Hc;
    }
}

// ---- scan pass 2a: 64 groups x 16 chunks -> group aggregates only ----
__global__ void scan2a_kernel(const float* __restrict__ P, const float* __restrict__ Hc,
                              float* __restrict__ Pg, float* __restrict__ Hg){
    const int g  = blockIdx.x;          // 0..63
    const int j4 = threadIdx.x * 4;     // 128 threads
    float4 pc = {1.f,1.f,1.f,1.f}, hc = {0.f,0.f,0.f,0.f};
    #pragma unroll
    for (int i = 0; i < GCH; i++){
        size_t o = (size_t)(g * GCH + i) * H + j4;
        float4 P4 = *(const float4*)(P + o);
        float4 H4 = *(const float4*)(Hc + o);
        hc.x = fmaf(P4.x, hc.x, H4.x); pc.x *= P4.x;
        hc.y = fmaf(P4.y, hc.y, H4.y); pc.y *= P4.y;
        hc.z = fmaf(P4.z, hc.z, H4.z); pc.z *= P4.z;
        hc.w = fmaf(P4.w, hc.w, H4.w); pc.w *= P4.w;
    }
    *(float4*)(Pg + (size_t)g * H + j4) = pc;
    *(float4*)(Hg + (size_t)g * H + j4) = hc;
}

// ---- scan pass 3: group prefix folded inline from Pg/Hg (same fmaf order as old scan2b),
// ---- then chunk folds; apply; y=C*h bf16 [T][H] ----
__global__ void scan3_kernel(const unsigned short* __restrict__ gT, const unsigned short* __restrict__ bxT,
                             const unsigned short* __restrict__ CT,
                             const float* __restrict__ P, const float* __restrict__ Hc,
                             const float* __restrict__ Pg, const float* __restrict__ Hg,
                             unsigned short* __restrict__ yb){
    int idx = blockIdx.x * 256 + threadIdx.x;
    int j4 = (idx & 127) * 4;
    int c  = idx >> 7;                  // wave-uniform (0..NC-1)
    int nb = j4 >> 5, jj = j4 & 31;
    int grp = c >> 4;                   // NC/GCH = 64 groups
    float4 h = {0.f, 0.f, 0.f, 0.f};
    for (int g = 0; g < grp; ++g){      // exclusive group prefix (== old Cg[grp])
        float4 P4 = *(const float4*)(Pg + (size_t)g * H + j4);
        float4 H4 = *(const float4*)(Hg + (size_t)g * H + j4);
        h.x = fmaf(P4.x, h.x, H4.x);
        h.y = fmaf(P4.y, h.y, H4.y);
        h.z = fmaf(P4.z, h.z, H4.z);
        h.w = fmaf(P4.w, h.w, H4.w);
    }
    for (int cc = grp << 4; cc < c; ++cc){          // <=15 L2-hot folds, wave-uniform count
        float4 P4 = *(const float4*)(P + (size_t)cc * H + j4);
        float4 H4 = *(const float4*)(Hc + (size_t)cc * H + j4);
        h.x = fmaf(P4.x, h.x, H4.x);
        h.y = fmaf(P4.y, h.y, H4.y);
        h.z = fmaf(P4.z, h.z, H4.z);
        h.w = fmaf(P4.w, h.w, H4.w);
    }
    size_t off = (size_t)nb * SLAB + (size_t)c * CHUNK * 32 + jj;
    size_t yo  = (size_t)c * CHUNK * H + j4;
    #pragma unroll 8
    for (int i = 0; i < CHUNK; i++){
        ushort4 gv = *(const ushort4*)(gT + off);
        ushort4 bv = *(const ushort4*)(bxT + off);
        ushort4 cv = *(const ushort4*)(CT + off);
        h.x = fmaf(expf(bf2f(gv.x)), h.x, bf2f(bv.x));
        h.y = fmaf(expf(bf2f(gv.y)), h.y, bf2f(bv.y));
        h.z = fmaf(expf(bf2f(gv.z)), h.z, bf2f(bv.z));
        h.w = fmaf(expf(bf2f(gv.w)), h.w, bf2f(bv.w));
        ushort4 o;
        o.x = f2bf(bf2f(cv.x) * h.x);
        o.y = f2bf(bf2f(cv.y) * h.y);
        o.z = f2bf(bf2f(cv.z) * h.z);
        o.w = f2bf(bf2f(cv.w) * h.w);
        *(ushort4*)(yb + yo) = o;
        off += 32; yo += H;
    }
}

// ---- scan pass 3 + fused output head (layer 1): y staged in LDS, never hits HBM.
// ---- Each block: rows 64*blockIdx .. +63, all 512 cols. Dot order identical to final_kernel.
__global__ __launch_bounds__(256) void scan3f_kernel(
    const unsigned short* __restrict__ gT, const unsigned short* __restrict__ bxT,
    const unsigned short* __restrict__ CT,
    const float* __restrict__ P, const float* __restrict__ Hc,
    const float* __restrict__ Pg, const float* __restrict__ Hg,
    const unsigned short* __restrict__ xb,
    const float* __restrict__ Wout, const float* __restrict__ bout,
    const float* __restrict__ Wskip,
    float* __restrict__ out){
    __shared__ unsigned short ystage[64 * 512];   // 64 KB
    const int tid = threadIdx.x;
    int idx = blockIdx.x * 256 + tid;
    int j4 = (idx & 127) * 4;
    int c  = idx >> 7;                  // wave-uniform
    int nb = j4 >> 5, jj = j4 & 31;
    int grp = c >> 4;
    float4 h = {0.f, 0.f, 0.f, 0.f};
    for (int g = 0; g < grp; ++g){
        float4 P4 = *(const float4*)(Pg + (size_t)g * H + j4);
        float4 H4 = *(const float4*)(Hg + (size_t)g * H + j4);
        h.x = fmaf(P4.x, h.x, H4.x);
        h.y = fmaf(P4.y, h.y, H4.y);
        h.z = fmaf(P4.z, h.z, H4.z);
        h.w = fmaf(P4.w, h.w, H4.w);
    }
    for (int cc = grp << 4; cc < c; ++cc){
        float4 P4 = *(const float4*)(P + (size_t)cc * H + j4);
        float4 H4 = *(const float4*)(Hc + (size_t)cc * H + j4);
        h.x = fmaf(P4.x, h.x, H4.x);
        h.y = fmaf(P4.y, h.y, H4.y);
        h.z = fmaf(P4.z, h.z, H4.z);
        h.w = fmaf(P4.w, h.w, H4.w);
    }
    size_t off = (size_t)nb * SLAB + (size_t)c * CHUNK * 32 + jj;
    const int lrow = (tid >> 7) * 32;   // local row base (two chunks per block)
    #pragma unroll 8
    for (int i = 0; i < CHUNK; i++){
        ushort4 gv = *(const ushort4*)(gT + off);
        ushort4 bv = *(const ushort4*)(bxT + off);
        ushort4 cv = *(const ushort4*)(CT + off);
        h.x = fmaf(expf(bf2f(gv.x)), h.x, bf2f(bv.x));
        h.y = fmaf(expf(bf2f(gv.y)), h.y, bf2f(bv.y));
        h.z = fmaf(expf(bf2f(gv.z)), h.z, bf2f(bv.z));
        h.w = fmaf(expf(bf2f(gv.w)), h.w, bf2f(bv.w));
        ushort4 o;
        o.x = f2bf(bf2f(cv.x) * h.x);
        o.y = f2bf(bf2f(cv.y) * h.y);
        o.z = f2bf(bf2f(cv.z) * h.z);
        o.w = f2bf(bf2f(cv.w) * h.w);
        *(ushort4*)(&ystage[(lrow + i) * 512 + j4]) = o;
        off += 32;
    }
    __syncthreads();

    // output head for this block's 64 rows
    const int wave = tid >> 6;
    const int lane = tid & 63;
    const float4* W4 = (const float4*)Wout;
    const float4* S4 = (const float4*)Wskip;
    const float b0 = bout[0], b1 = bout[1], b2 = bout[2], b3 = bout[3];
    for (int rr = 0; rr < 16; ++rr){
        const int r = wave * 16 + rr;
        const int t = blockIdx.x * 64 + r;
        float s0 = 0.f, s1 = 0.f, s2 = 0.f, s3 = 0.f;
        #pragma unroll
        for (int k = lane; k < H; k += 64){
            float yv = bf2f(ystage[r * 512 + k]);
            float4 w = W4[k];
            s0 = fmaf(yv, w.x, s0); s1 = fmaf(yv, w.y, s1);
            s2 = fmaf(yv, w.z, s2); s3 = fmaf(yv, w.w, s3);
        }
        #pragma unroll
        for (int k = lane; k < OBS; k += 64){
            float xv = bf2f(xb[(size_t)t * OBS + k]);
            float4 w = S4[k];
            s0 = fmaf(xv, w.x, s0); s1 = fmaf(xv, w.y, s1);
            s2 = fmaf(xv, w.z, s2); s3 = fmaf(xv, w.w, s3);
        }
        #pragma unroll
        for (int o = 32; o > 0; o >>= 1){
            s0 += __shfl_down(s0, o);
            s1 += __shfl_down(s1, o);
            s2 += __shfl_down(s2, o);
            s3 += __shfl_down(s3, o);
        }
        if (lane == 0){
            out[(size_t)t * 4 + 0] = s0 + b0;
            out[(size_t)t * 4 + 1] = s1 + b1;
            out[(size_t)t * 4 + 2] = s2 + b2;
            out[(size_t)t * 4 + 3] = s3 + b3;
        }
    }
}

extern "C" void kernel_launch(void* const* d_in, const int* in_sizes, int n_in,
                              void* d_out, int out_size, void* d_ws, size_t ws_size,
                              hipStream_t stream)
{
    const float* x     = (const float*)d_in[0];
    const float* W_in0 = (const float*)d_in[1];
    const float* W_B0  = (const float*)d_in[2];
    const float* W_C0  = (const float*)d_in[3];
    const float* W_d0  = (const float*)d_in[4];
    const float* A0    = (const float*)d_in[5];
    const float* W_in1 = (const float*)d_in[6];
    const float* W_B1  = (const float*)d_in[7];
    const float* W_C1  = (const float*)d_in[8];
    const float* W_d1  = (const float*)d_in[9];
    const float* A1    = (const float*)d_in[10];
    const float* Wout  = (const float*)d_in[11];
    const float* bout  = (const float*)d_in[12];
    const float* Wskip = (const float*)d_in[13];
    float* out = (float*)d_out;

    char* ws = (char*)d_ws;
    size_t off = 0;
    auto alloc = [&](size_t bytes) -> void* {
        void* p = ws + off;
        off += (bytes + 255) & ~(size_t)255;
        return p;
    };
    unsigned short* xb  = (unsigned short*)alloc((size_t)T_SIZE * OBS * 2);
    unsigned short* yb  = (unsigned short*)alloc((size_t)T_SIZE * H * 2);  // layer0 y
    unsigned short* Wt0 = (unsigned short*)alloc((size_t)4 * H * OBS * 2);
    unsigned short* Wt1 = (unsigned short*)alloc((size_t)4 * H * H * 2);
    unsigned short* gT  = (unsigned short*)alloc((size_t)T_SIZE * H * 2);
    unsigned short* bxT = (unsigned short*)alloc((size_t)T_SIZE * H * 2);
    unsigned short* CT  = (unsigned short*)alloc((size_t)T_SIZE * H * 2);
    float* Pbuf = (float*)alloc((size_t)NC * H * 4);
    float* Hbuf = (float*)alloc((size_t)NC * H * 4);
    float* Pg   = (float*)alloc((size_t)NGRP * H * 4);
    float* Hg   = (float*)alloc((size_t)NGRP * H * 4);
    (void)ws_size; (void)in_sizes; (void)n_in; (void)out_size;

    // ---- merged precision casts / weight transposes (1 dispatch) ----
    prep_kernel<<<14336, 256, 0, stream>>>(x, xb,
                                           W_in0, W_B0, W_C0, W_d0, Wt0,
                                           W_in1, W_B1, W_C1, W_d1, Wt1);

    dim3 ggrid(16, 256);                 // flat-swizzled inside the kernel
    const int sgrid = NC * 128 / 256;    // 512 blocks

    // ---- layer 0 ----
    gemm_layer_kernel<OBS><<<ggrid, 256, 0, stream>>>(xb, Wt0, A0, gT, bxT, CT, Pbuf, Hbuf);
    scan2a_kernel<<<NGRP, 128, 0, stream>>>(Pbuf, Hbuf, Pg, Hg);
    scan3_kernel<<<sgrid, 256, 0, stream>>>(gT, bxT, CT, Pbuf, Hbuf, Pg, Hg, yb);

    // ---- layer 1 (output head fused into scan3f; y1 never materialized) ----
    gemm_layer_kernel<H><<<ggrid, 256, 0, stream>>>(yb, Wt1, A1, gT, bxT, CT, Pbuf, Hbuf);
    scan2a_kernel<<<NGRP, 128, 0, stream>>>(Pbuf, Hbuf, Pg, Hg);
    scan3f_kernel<<<sgrid, 256, 0, stream>>>(gT, bxT, CT, Pbuf, Hbuf, Pg, Hg,
                                             xb, Wout, bout, Wskip, out);
}